// Round 16
// baseline (34.926 us; speedup 1.0000x reference)
//
#include <hip/hip_runtime.h>
#include <hip/hip_bf16.h>

#define M 256
#define NOUT 1024
#define KTOT 16384
#define IN 1024
#define RANK 16
#define NKC 32          // split-K factor
#define KCHUNK 512      // K per block (32 i-values)
#define NPH 8           // phases per block (BK=64 -> 4 k-steps/phase)

typedef __attribute__((ext_vector_type(8)))  short bf16x8_t;
typedef __attribute__((ext_vector_type(4)))  float f32x4_t;
typedef __attribute__((ext_vector_type(16))) float f32x16_t;
typedef __attribute__((ext_vector_type(8)))  unsigned short u16x8_t;

static __device__ __forceinline__ unsigned short f2bf(float f) {
  unsigned u = __builtin_bit_cast(unsigned, f);
  u += 0x7FFFu + ((u >> 16) & 1u);   // round-to-nearest-even
  return (unsigned short)(u >> 16);
}
static __device__ __forceinline__ float bf2f(unsigned short h) {
  unsigned u = ((unsigned)h) << 16;
  return __builtin_bit_cast(float, u);
}
// single-instruction packed fp32x2 -> bf16x2
static __device__ __forceinline__ unsigned cvtpk1(float lo, float hi) {
  unsigned r;
  asm("v_cvt_pk_bf16_f32 %0, %1, %2" : "=v"(r) : "v"(lo), "v"(hi));
  return r;
}
// A-frag build: 8 products s*c[e] -> bf16x8 via 4 cvt_pk
static __device__ __forceinline__ bf16x8_t mulcvt8(float s, const float* c) {
  union { bf16x8_t v; unsigned u[4]; } r;
  #pragma unroll
  for (int e = 0; e < 4; ++e)
    r.u[e] = cvtpk1(s * c[2 * e], s * c[2 * e + 1]);
  return r.v;
}
// fp32x4 -> bf16x4 -> one 8 B LDS store (2 cvt_pk)
static __device__ __forceinline__ void dsw4pk(unsigned short* dst, float4 v) {
  unsigned a = cvtpk1(v.x, v.y), b = cvtpk1(v.z, v.w);
  unsigned long long q = ((unsigned long long)b << 32) | (unsigned long long)a;
  *(unsigned long long*)dst = q;   // 8-B aligned by construction
}

// GEMM, X NEVER MATERIALIZED: part[kc][b][o] (bf16) =
//   sum_{k in chunk kc} X[b,k] * W[o,k],  X[b,16i+r] = input[b,i]*coef[b,r]
// via mfma_f32_32x32x16_bf16 (A = X-frag built in registers, B = W-frag
// from fragment-major bf16 LDS, conflict-free b128 reads).
// Block: 256 b x 64 o x K=512; 512 threads (8 waves). Grid 512 = 16 ot x
// 32 kc -> 2 blocks/CU (49 KB LDS). RAW barriers (lgkmcnt only -- no vmcnt
// drain, VMEM targets are registers).
//
// NEW vs R15: W register prefetch deepened to FOUR named sets = DSW2
// consumes data issued THREE phases earlier (~2000+ cy cover vs ~1200 cy
// loaded HBM latency; R15's 2 sets gave only ~1 phase and stalled every
// phase in the pre-ds_write register wait). In-flight W: 128 KB/CU.
__global__ __launch_bounds__(512, 4) void gemm_kernel(
    const float* __restrict__ input, const float* __restrict__ coef,
    const float* __restrict__ W, unsigned short* __restrict__ part)
{
  __shared__ float in_lds[256 * 33];                    // 33 KB, pad -> 2-way max
  __shared__ __align__(16) unsigned short Ws[2][4096];  // 2 x 8 KB frag-major

  const int tid = threadIdx.x;                  // 0..511
  const int wid = tid >> 6, lane = tid & 63;
  const int l31 = lane & 31, l5 = lane >> 5;
  const int bq = wid >> 1, oc = wid & 1;        // wave: b-base bq*64, o-half oc*32
  const int bbase = bq * 64;

  // XCD swizzle (bijective for 512): 8 ot-groups per XCD share kc slices.
  const int lin = blockIdx.y * 16 + blockIdx.x;
  const int swb = (lin & 7) * 64 + (lin >> 3);
  const int ot = swb & 15, kc = swb >> 4;

  const int o0 = ot * 64;
  const int kb0 = kc * KCHUNK;
  const int i0 = kc * 32;                       // 32 i-values per block

  f32x16_t acc0 = (f32x16_t)(0.0f), acc1 = (f32x16_t)(0.0f);

  // ---- prologue A: input slice [256 b][32 i] -> padded LDS (stride 33) ----
  {
    int b = tid >> 1, half = tid & 1;
    const float* src = input + (size_t)b * IN + i0 + half * 16;
    float* dst = in_lds + b * 33 + half * 16;
    #pragma unroll
    for (int j = 0; j < 16; ++j) dst[j] = src[j];
  }

  // coef preload: frag0 b = bbase+l31, frag1 b = bbase+32+l31; r = l5*8+e
  float c0[8], c1[8];
  {
    const float* cp0 = coef + (size_t)(bbase + l31) * RANK + l5 * 8;
    const float* cp1 = coef + (size_t)(bbase + 32 + l31) * RANK + l5 * 8;
    #pragma unroll
    for (int e = 0; e < 8; ++e) { c0[e] = cp0[e]; c1[e] = cp1[e]; }
  }
  const int ib0 = (bbase + l31) * 33, ib1 = (bbase + 32 + l31) * 33;

  // W stage coords (BK=64: 64 rows x 16 float4, 2 float4/thread)
  const float* wgp0 = W + (size_t)(o0 + (tid >> 4)) * KTOT + kb0 + (tid & 15) * 4;
  const float* wgp1 = wgp0 + (size_t)32 * KTOT;
  const int wd0 = ((((tid & 15) >> 1) * 64 + (tid >> 4)) * 8 + (tid & 1) * 4);
  const int wd1 = wd0 + 32 * 8;

  float4 wA0, wA1, wB0, wB1, wC0, wC1, wD0, wD1;   // FOUR prefetch sets

  #define SB __builtin_amdgcn_sched_barrier(0);
  #define BARX                                                               \
    SB asm volatile("s_waitcnt lgkmcnt(0)" ::: "memory");                    \
    __builtin_amdgcn_s_barrier(); SB

  #define LOADW(S, P)                                                        \
    { w##S##0 = *(const float4*)(wgp0 + (P) * 64);                           \
      w##S##1 = *(const float4*)(wgp1 + (P) * 64); }

  #define DSW2(S, BUF)                                                       \
    { dsw4pk(&Ws[BUF][wd0], w##S##0); dsw4pk(&Ws[BUF][wd1], w##S##1); }

  #define KSTEP(TL, BUF)                                                     \
    {                                                                        \
      float in0 = in_lds[ib0 + (TL)];                                        \
      float in1 = in_lds[ib1 + (TL)];                                        \
      bf16x8_t af0 = mulcvt8(in0, c0);                                       \
      bf16x8_t af1 = mulcvt8(in1, c1);                                       \
      bf16x8_t bf = *(const bf16x8_t*)                                       \
          &Ws[BUF][((((TL) & 3) * 2 + l5) * 64 + oc * 32 + l31) * 8];        \
      __builtin_amdgcn_s_setprio(1);                                         \
      acc0 = __builtin_amdgcn_mfma_f32_32x32x16_bf16(af0, bf, acc0, 0, 0, 0);\
      acc1 = __builtin_amdgcn_mfma_f32_32x32x16_bf16(af1, bf, acc1, 0, 0, 0);\
      __builtin_amdgcn_s_setprio(0);                                         \
    }

  // phase p: [LOADW(set p%4, p+4)] ; 4 k-steps from Ws[p&1] ;
  //          DSW2(set (p+1)%4 -> Ws[(p+1)&1]) ; raw barrier.
  #define PHASE(P, SC, SN, DOL)                                              \
    if (DOL) { LOADW(SC, (P) + 4) }                                          \
    KSTEP((P) * 4,     (P) & 1)  KSTEP((P) * 4 + 1, (P) & 1)                 \
    KSTEP((P) * 4 + 2, (P) & 1)  KSTEP((P) * 4 + 3, (P) & 1)                 \
    if ((P) + 1 < NPH) { DSW2(SN, ((P) + 1) & 1) }                           \
    BARX

  // ---- prologue B: W phases 0..3 in flight; write phase 0 ----
  LOADW(A, 0)
  LOADW(B, 1)
  LOADW(C, 2)
  LOADW(D, 3)
  DSW2(A, 0)
  BARX

  PHASE(0, A, B, 1)  PHASE(1, B, C, 1)  PHASE(2, C, D, 1)  PHASE(3, D, A, 1)
  PHASE(4, A, B, 0)  PHASE(5, B, C, 0)  PHASE(6, C, D, 0)  PHASE(7, D, A, 0)

  // ---- epilogue: D row(b-part)=(q&3)+8*(q>>2)+4*l5, col(o)=l31 ----
  unsigned short* pp = part + (size_t)kc * (M * NOUT);
  const int ocol = o0 + oc * 32 + l31;
  #pragma unroll
  for (int q = 0; q < 8; ++q) {
    int brow = bbase + (2 * q & 3) + 8 * (2 * q >> 2) + 4 * l5;
    // pairs (2q, 2q+1) share (row-group), differ by +1 in row
    unsigned v0 = cvtpk1(acc0[2 * q], acc0[2 * q + 1]);
    unsigned v1 = cvtpk1(acc1[2 * q], acc1[2 * q + 1]);
    pp[(size_t)brow * NOUT + ocol]            = (unsigned short)(v0 & 0xFFFF);
    pp[(size_t)(brow + 1) * NOUT + ocol]      = (unsigned short)(v0 >> 16);
    pp[(size_t)(brow + 32) * NOUT + ocol]     = (unsigned short)(v1 & 0xFFFF);
    pp[(size_t)(brow + 33) * NOUT + ocol]     = (unsigned short)(v1 >> 16);
  }
  #undef LOADW
  #undef DSW2
  #undef KSTEP
  #undef PHASE
  #undef BARX
  #undef SB
}

// out[b][o] = sum_kc bf2f(part[kc][b][o]) + sum_r bias[o][r]*coef[b][r]
__global__ __launch_bounds__(256) void reduce_bias_kernel(
    const unsigned short* __restrict__ part, const float* __restrict__ bias,
    const float* __restrict__ coef, float* __restrict__ out)
{
  int t = blockIdx.x * 256 + threadIdx.x;
  int idx8 = t * 8;                       // 8 consecutive outputs, same b
  int b = idx8 >> 10, o = idx8 & 1023;

  float s[8];
  #pragma unroll
  for (int j = 0; j < 8; ++j) s[j] = 0.f;

  #pragma unroll
  for (int c = 0; c < NKC; ++c) {
    u16x8_t v = *(const u16x8_t*)(part + (size_t)c * (M * NOUT) + idx8);
    #pragma unroll
    for (int j = 0; j < 8; ++j) s[j] += bf2f(v[j]);
  }

  const f32x4_t* cr = (const f32x4_t*)(coef + (size_t)b * RANK);
  f32x4_t c0 = cr[0], c1 = cr[1], c2 = cr[2], c3 = cr[3];
  #pragma unroll
  for (int j = 0; j < 8; ++j) {
    const f32x4_t* br = (const f32x4_t*)(bias + (size_t)(o + j) * RANK);
    f32x4_t b0 = br[0], b1 = br[1], b2 = br[2], b3 = br[3];
    float bb = 0.f;
    #pragma unroll
    for (int e = 0; e < 4; ++e)
      bb += b0[e] * c0[e] + b1[e] * c1[e] + b2[e] * c2[e] + b3[e] * c3[e];
    s[j] += bb;
  }
  float4* dst = (float4*)(out + idx8);
  dst[0] = make_float4(s[0], s[1], s[2], s[3]);
  dst[1] = make_float4(s[4], s[5], s[6], s[7]);
}

extern "C" void kernel_launch(void* const* d_in, const int* in_sizes, int n_in,
                              void* d_out, int out_size, void* d_ws, size_t ws_size,
                              hipStream_t stream) {
  const float* input = (const float*)d_in[0];   // (256, 1024)
  const float* coef  = (const float*)d_in[1];   // (256, 16)
  const float* W     = (const float*)d_in[2];   // (1024, 1024, 16) -> (1024, 16384)
  const float* bias  = (const float*)d_in[3];   // (1024, 16)
  float* out = (float*)d_out;                   // (256, 1024)

  unsigned short* part = (unsigned short*)d_ws;   // 16 MiB bf16 partials

  gemm_kernel<<<dim3(16, 32), 512, 0, stream>>>(input, coef, W, part);
  reduce_bias_kernel<<<(M * NOUT) / (256 * 8), 256, 0, stream>>>(part, bias, coef, out);
}